// Round 1
// baseline (631.597 us; speedup 1.0000x reference)
//
#include <hip/hip_runtime.h>
#include <hip/hip_bf16.h>

// Problem constants
#define B_ 16384
#define F_ 128
#define D_ 256
#define A_ 256
#define T_ 64
#define DECAY_ 0.9f

__device__ __forceinline__ float tanh_fast(float x) {
    // tanh(x) = 1 - 2/(1+exp(2x)); exact at +-inf, ~1ulp rcp fine for 0.1 threshold
    float e = __expf(2.0f * x);
    return 1.0f - 2.0f * __builtin_amdgcn_rcpf(e + 1.0f);
}
__device__ __forceinline__ float sigmoid_fast(float x) {
    return __builtin_amdgcn_rcpf(1.0f + __expf(-x));
}
__device__ __forceinline__ bool get_mask(const void* mp, int mflag, int row) {
    if (mflag) return ((const unsigned char*)mp)[row] != 0;
    return ((const int*)mp)[row] != 0;
}

// ---- mask dtype probe: int32 0/1 array -> all words <=1; packed bools -> some word >1 ----
__global__ __launch_bounds__(256) void mask_probe(const unsigned int* m, int* flag) {
    __shared__ int f;
    if (threadIdx.x == 0) f = 0;
    __syncthreads();
    int any = 0;
    for (int i = threadIdx.x; i < B_ / 4; i += 256) any |= (m[i] > 1u) ? 1 : 0;
    if (any) atomicOr(&f, 1);
    __syncthreads();
    if (threadIdx.x == 0) flag[0] = f;
}

// ---- transpose weights: W_ih[768,128]->WTih[128,768], W_hh[768,256]->WThh[256,768], Wc[256,256]->WcT ----
__global__ __launch_bounds__(256) void transpose_w(const float* Wih, const float* Whh, const float* Wc,
                                                   float* WTih, float* WThh, float* WcT) {
    int idx = blockIdx.x * 256 + threadIdx.x;
    if (idx < 128 * 768) {
        int k = idx / 768, j = idx % 768;
        WTih[idx] = Wih[j * 128 + k];
    } else if (idx < 128 * 768 + 256 * 768) {
        int t = idx - 128 * 768;
        int k = t / 768, j = t % 768;
        WThh[t] = Whh[j * 256 + k];
    } else if (idx < 128 * 768 + 256 * 768 + 256 * 256) {
        int t = idx - (128 * 768 + 256 * 768);
        int d = t / 256, a = t % 256;
        WcT[t] = Wc[a * 256 + d];
    }
}

// ---- hist = tanh(tokens) [T,D]; tok_proj = hist @ Wh.T + bh [T,A] ----
__global__ __launch_bounds__(256) void prep_kernel(const float* tokens, const float* Wh, const float* bh,
                                                   float* hist, float* tokp) {
    int t = blockIdx.x, tid = threadIdx.x;
    __shared__ float hrow[D_];
    float hv = tanh_fast(tokens[t * D_ + tid]);
    hrow[tid] = hv;
    hist[t * D_ + tid] = hv;
    __syncthreads();
    float acc = bh[tid];
    const float* wr = &Wh[tid * D_];
    for (int d = 0; d < D_; d++) acc += hrow[d] * wr[d];
    tokp[t * A_ + tid] = acc;
}

// ---- GRU: 32 rows/block. gi = x@W_ih.T, gh = h@W_hh.T; fused gates; writes h_new (ws) + h_out ----
__global__ __launch_bounds__(256) void gru_kernel(const float* __restrict__ features, const float* __restrict__ h,
                                                  const void* maskp, const int* mflagp,
                                                  const float* __restrict__ WTih, const float* __restrict__ WThh,
                                                  const float* __restrict__ b_ih, const float* __restrict__ b_hh,
                                                  float* __restrict__ hnew_ws, float* __restrict__ hout) {
    __shared__ float fl[32 * 129];
    __shared__ float hl[32 * 257];
    int tid = threadIdx.x;
    int b0 = blockIdx.x * 32;
    int mflag = mflagp[0];
    for (int i = tid; i < 32 * F_; i += 256) fl[(i >> 7) * 129 + (i & 127)] = features[(size_t)b0 * F_ + i];
    for (int i = tid; i < 32 * D_; i += 256) hl[(i >> 8) * 257 + (i & 255)] = h[(size_t)b0 * D_ + i];
    __syncthreads();

    int cg = tid & 15;   // column quad group (4 cols each -> 64 cols/chunk)
    int rg = tid >> 4;   // row pair group
    int r0 = rg * 2;

    for (int c = 0; c < 4; c++) {
        int g = c * 64 + cg * 4;  // gate column base within [0,256)
        float ar[2][4] = {}, az[2][4] = {}, ain[2][4] = {}, ahn[2][4] = {};

        // K=128 over features (W_ih rows r,z,n)
        for (int k = 0; k < F_; k++) {
            float x0 = fl[r0 * 129 + k];
            float x1 = fl[(r0 + 1) * 129 + k];
            float4 wr4 = *(const float4*)&WTih[k * 768 + g];
            float4 wz4 = *(const float4*)&WTih[k * 768 + 256 + g];
            float4 wn4 = *(const float4*)&WTih[k * 768 + 512 + g];
            const float* wr = (const float*)&wr4;
            const float* wz = (const float*)&wz4;
            const float* wn = (const float*)&wn4;
#pragma unroll
            for (int j = 0; j < 4; j++) {
                ar[0][j] += x0 * wr[j]; ar[1][j] += x1 * wr[j];
                az[0][j] += x0 * wz[j]; az[1][j] += x1 * wz[j];
                ain[0][j] += x0 * wn[j]; ain[1][j] += x1 * wn[j];
            }
        }
        // K=256 over h (W_hh rows r,z,n)
        for (int k = 0; k < D_; k++) {
            float x0 = hl[r0 * 257 + k];
            float x1 = hl[(r0 + 1) * 257 + k];
            float4 wr4 = *(const float4*)&WThh[k * 768 + g];
            float4 wz4 = *(const float4*)&WThh[k * 768 + 256 + g];
            float4 wn4 = *(const float4*)&WThh[k * 768 + 512 + g];
            const float* wr = (const float*)&wr4;
            const float* wz = (const float*)&wz4;
            const float* wn = (const float*)&wn4;
#pragma unroll
            for (int j = 0; j < 4; j++) {
                ar[0][j] += x0 * wr[j]; ar[1][j] += x1 * wr[j];
                az[0][j] += x0 * wz[j]; az[1][j] += x1 * wz[j];
                ahn[0][j] += x0 * wn[j]; ahn[1][j] += x1 * wn[j];
            }
        }
        // epilogue: gates + masked select
#pragma unroll
        for (int i = 0; i < 2; i++) {
            int row = r0 + i;
            int grow = b0 + row;
            bool m = get_mask(maskp, mflag, grow);
            float4 hnv, hov;
            float* hnp = (float*)&hnv;
            float* hop = (float*)&hov;
#pragma unroll
            for (int j = 0; j < 4; j++) {
                int gc = g + j;
                float rv = sigmoid_fast(ar[i][j] + b_ih[gc] + b_hh[gc]);
                float zv = sigmoid_fast(az[i][j] + b_ih[256 + gc] + b_hh[256 + gc]);
                float nv = tanh_fast(ain[i][j] + b_ih[512 + gc] + rv * (ahn[i][j] + b_hh[512 + gc]));
                float hvv = hl[row * 257 + gc];
                float hn = (1.0f - zv) * nv + zv * hvv;
                hnp[j] = hn;
                hop[j] = m ? hn : hvv;
            }
            *(float4*)&hnew_ws[(size_t)grow * D_ + g] = hnv;
            *(float4*)&hout[(size_t)grow * D_ + g] = hov;
        }
    }
}

// ---- ctx = h_new @ Wc.T + bc : 64 rows/block ----
__global__ __launch_bounds__(256) void ctx_kernel(const float* __restrict__ hnew_ws, const float* __restrict__ WcT,
                                                  const float* __restrict__ bc, float* __restrict__ ctx_ws) {
    __shared__ float hl[64 * 257];
    int tid = threadIdx.x;
    int b0 = blockIdx.x * 64;
    for (int i = tid; i < 64 * D_; i += 256) hl[(i >> 8) * 257 + (i & 255)] = hnew_ws[(size_t)b0 * D_ + i];
    __syncthreads();
    int cg = tid & 15, rg = tid >> 4;
    int r0 = rg * 4;
    for (int c = 0; c < 4; c++) {
        int a0 = c * 64 + cg * 4;
        float acc[4][4] = {};
        for (int k = 0; k < D_; k++) {
            float4 wv = *(const float4*)&WcT[k * A_ + a0];
            const float* w = (const float*)&wv;
#pragma unroll
            for (int i = 0; i < 4; i++) {
                float x = hl[(r0 + i) * 257 + k];
#pragma unroll
                for (int j = 0; j < 4; j++) acc[i][j] += x * w[j];
            }
        }
#pragma unroll
        for (int i = 0; i < 4; i++) {
            float4 o;
            float* op = (float*)&o;
#pragma unroll
            for (int j = 0; j < 4; j++) op[j] = acc[i][j] + bc[a0 + j];
            *(float4*)&ctx_ws[(size_t)(b0 + r0 + i) * A_ + a0] = o;
        }
    }
}

// ---- attention: scores(tanh) -> softmax (in registers) -> emb -> masked accumulator update ----
// 8 rows/block, 4 waves, each wave owns 2 rows; lanes parallel over A (quad each).
__global__ __launch_bounds__(256) void attn_kernel(const float* __restrict__ ctx_ws, const float* __restrict__ tokp,
                                                   const float* __restrict__ hist, const float* __restrict__ v,
                                                   const float* __restrict__ accum, const void* maskp,
                                                   const int* mflagp, float* __restrict__ out_emb) {
    __shared__ float tl[T_ * A_];   // tok_proj, then reused for hist
    __shared__ float wl[8 * T_];
    int tid = threadIdx.x;
    int b0 = blockIdx.x * 8;
    int wave = tid >> 6, lane = tid & 63;
    int mflag = mflagp[0];

    for (int i = tid; i < T_ * A_; i += 256) tl[i] = tokp[i];
    __syncthreads();

    int a0 = lane * 4;
    float4 v4 = *(const float4*)&v[a0];
    const float* vv = (const float*)&v4;
    int r0 = wave * 2;
    float4 c40 = *(const float4*)&ctx_ws[(size_t)(b0 + r0) * A_ + a0];
    float4 c41 = *(const float4*)&ctx_ws[(size_t)(b0 + r0 + 1) * A_ + a0];
    const float* cc0 = (const float*)&c40;
    const float* cc1 = (const float*)&c41;

    float sc[2] = {0.f, 0.f};
    for (int t = 0; t < T_; t++) {
        float4 tk4 = *(const float4*)&tl[t * A_ + a0];
        const float* tk = (const float*)&tk4;
        float p0 = 0.f, p1 = 0.f;
#pragma unroll
        for (int j = 0; j < 4; j++) {
            p0 += tanh_fast(tk[j] + cc0[j]) * vv[j];
            p1 += tanh_fast(tk[j] + cc1[j]) * vv[j];
        }
#pragma unroll
        for (int m = 1; m < 64; m <<= 1) {
            p0 += __shfl_xor(p0, m, 64);
            p1 += __shfl_xor(p1, m, 64);
        }
        if (lane == t) { sc[0] = p0; sc[1] = p1; }
    }

    // softmax across T (lane t holds score[r][t]); bv dropped (softmax-invariant)
#pragma unroll
    for (int i = 0; i < 2; i++) {
        float x = sc[i];
        float mx = x;
#pragma unroll
        for (int m = 1; m < 64; m <<= 1) mx = fmaxf(mx, __shfl_xor(mx, m, 64));
        float e = __expf(x - mx);
        float s = e;
#pragma unroll
        for (int m = 1; m < 64; m <<= 1) s += __shfl_xor(s, m, 64);
        wl[(r0 + i) * T_ + lane] = e * __builtin_amdgcn_rcpf(s);
    }
    __syncthreads();            // everyone done reading tok_proj
    for (int i = tid; i < T_ * D_; i += 256) tl[i] = hist[i];
    __syncthreads();

    // emb = weights @ hist ; lane owns d-quad a0
    float4 acc0 = {0, 0, 0, 0}, acc1 = {0, 0, 0, 0};
    for (int t = 0; t < T_; t++) {
        float4 h4 = *(const float4*)&tl[t * D_ + a0];
        float w0 = wl[r0 * T_ + t];
        float w1 = wl[(r0 + 1) * T_ + t];
        acc0.x += w0 * h4.x; acc0.y += w0 * h4.y; acc0.z += w0 * h4.z; acc0.w += w0 * h4.w;
        acc1.x += w1 * h4.x; acc1.y += w1 * h4.y; acc1.z += w1 * h4.z; acc1.w += w1 * h4.w;
    }
#pragma unroll
    for (int i = 0; i < 2; i++) {
        size_t row = (size_t)(b0 + r0 + i);
        bool m = get_mask(maskp, mflag, (int)row);
        float4 av = *(const float4*)&accum[row * D_ + a0];
        float4 ac = i == 0 ? acc0 : acc1;
        float4 o;
        o.x = m ? av.x * DECAY_ + ac.x : av.x;
        o.y = m ? av.y * DECAY_ + ac.y : av.y;
        o.z = m ? av.z * DECAY_ + ac.z : av.z;
        o.w = m ? av.w * DECAY_ + ac.w : av.w;
        *(float4*)&out_emb[row * D_ + a0] = o;
    }
}

extern "C" void kernel_launch(void* const* d_in, const int* in_sizes, int n_in,
                              void* d_out, int out_size, void* d_ws, size_t ws_size,
                              hipStream_t stream) {
    const float* features = (const float*)d_in[0];
    const float* h        = (const float*)d_in[1];
    const float* accum    = (const float*)d_in[2];
    const void*  maskp    = d_in[3];
    const float* tokens   = (const float*)d_in[4];
    const float* Wih      = (const float*)d_in[5];
    const float* Whh      = (const float*)d_in[6];
    const float* bih      = (const float*)d_in[7];
    const float* bhh      = (const float*)d_in[8];
    const float* Wh       = (const float*)d_in[9];
    const float* bh       = (const float*)d_in[10];
    const float* Wc       = (const float*)d_in[11];
    const float* bc       = (const float*)d_in[12];
    const float* v        = (const float*)d_in[13];
    // d_in[14] = bv : softmax-invariant, unused

    float* out = (float*)d_out;            // [B*D] emb_out, then [B*D] h_out
    float* ws = (float*)d_ws;
    float* WTih = ws;                                    // 128*768
    float* WThh = WTih + 128 * 768;                      // 256*768
    float* WcT  = WThh + 256 * 768;                      // 256*256
    float* hist = WcT + 256 * 256;                       // 64*256
    float* tokp = hist + 64 * 256;                       // 64*256
    float* hnew = tokp + 64 * 256;                       // B*256
    float* ctxb = hnew + (size_t)B_ * D_;                // B*256
    int*   mflag = (int*)(ctxb + (size_t)B_ * D_);

    hipLaunchKernelGGL(mask_probe, dim3(1), dim3(256), 0, stream,
                       (const unsigned int*)maskp, mflag);
    hipLaunchKernelGGL(transpose_w, dim3(1408), dim3(256), 0, stream,
                       Wih, Whh, Wc, WTih, WThh, WcT);
    hipLaunchKernelGGL(prep_kernel, dim3(64), dim3(256), 0, stream,
                       tokens, Wh, bh, hist, tokp);
    hipLaunchKernelGGL(gru_kernel, dim3(B_ / 32), dim3(256), 0, stream,
                       features, h, maskp, mflag, WTih, WThh, bih, bhh,
                       hnew, out + (size_t)B_ * D_);
    hipLaunchKernelGGL(ctx_kernel, dim3(B_ / 64), dim3(256), 0, stream,
                       hnew, WcT, bc, ctxb);
    hipLaunchKernelGGL(attn_kernel, dim3(B_ / 8), dim3(256), 0, stream,
                       ctxb, tokp, hist, v, accum, maskp, mflag, out);
}

// Round 2
// 155.876 us; speedup vs baseline: 4.0519x; 4.0519x over previous
//
#include <hip/hip_runtime.h>
#include <hip/hip_bf16.h>

#define B_ 16384
#define F_ 128
#define D_ 256
#define A_ 256
#define T_ 64
#define DECAY_ 0.9f

typedef __attribute__((ext_vector_type(8))) __bf16 bf16x8;
typedef __attribute__((ext_vector_type(4))) float f32x4;

__device__ __forceinline__ float tanh_fast(float x) {
    float e = __expf(2.0f * x);
    return 1.0f - 2.0f * __builtin_amdgcn_rcpf(e + 1.0f);
}
__device__ __forceinline__ float sigmoid_fast(float x) {
    return __builtin_amdgcn_rcpf(1.0f + __expf(-x));
}
__device__ __forceinline__ bool get_mask(const void* mp, int mflag, int row) {
    if (mflag) return ((const unsigned char*)mp)[row] != 0;
    return ((const int*)mp)[row] != 0;
}
__device__ __forceinline__ unsigned short bfbits(float f) {
    __bf16 h = (__bf16)f;
    return __builtin_bit_cast(unsigned short, h);
}
__device__ __forceinline__ float bits2f(unsigned short u) {
    return __builtin_bit_cast(float, ((unsigned)u) << 16);
}

// ---- mask dtype probe ----
__global__ __launch_bounds__(256) void mask_probe(const unsigned int* m, int* flag) {
    __shared__ int f;
    if (threadIdx.x == 0) f = 0;
    __syncthreads();
    int any = 0;
    for (int i = threadIdx.x; i < B_ / 4; i += 256) any |= (m[i] > 1u) ? 1 : 0;
    if (any) atomicOr(&f, 1);
    __syncthreads();
    if (threadIdx.x == 0) flag[0] = f;
}

// ---- convert weights fp32 -> bf16 (row-major, no transpose: W rows ARE the MFMA B^T layout) ----
__global__ __launch_bounds__(256) void convert_w(const float* Wih, const float* Whh, const float* Wc,
                                                 __bf16* Wihb, __bf16* Whhb, __bf16* Wcb) {
    const int n1 = 768 * 128, n2 = n1 + 768 * 256, n3 = n2 + 256 * 256;
    int i = (blockIdx.x * 256 + threadIdx.x) * 4;
    if (i < n1) {
#pragma unroll
        for (int j = 0; j < 4; ++j) Wihb[i + j] = (__bf16)Wih[i + j];
    } else if (i < n2) {
        int k = i - n1;
#pragma unroll
        for (int j = 0; j < 4; ++j) Whhb[k + j] = (__bf16)Whh[k + j];
    } else if (i < n3) {
        int k = i - n2;
#pragma unroll
        for (int j = 0; j < 4; ++j) Wcb[k + j] = (__bf16)Wc[k + j];
    }
}

// ---- hist = tanh(tokens) [T,D] bf16; tok_proj = hist @ Wh.T + bh [T,A] bf16 ----
__global__ __launch_bounds__(256) void prep_kernel(const float* tokens, const float* Wh, const float* bh,
                                                   __bf16* histb, __bf16* tokpb) {
    int t = blockIdx.x, tid = threadIdx.x;
    __shared__ float hrow[D_];
    float hv = tanh_fast(tokens[t * D_ + tid]);
    hrow[tid] = hv;
    histb[t * D_ + tid] = (__bf16)hv;
    __syncthreads();
    float acc = bh[tid];
    const float* wr = &Wh[tid * D_];
    for (int d = 0; d < D_; d++) acc += hrow[d] * wr[d];
    tokpb[t * A_ + tid] = (__bf16)acc;
}

// ---- fused GRU (MFMA) + ctx GEMM (MFMA) ----
// 32 rows/block, 4 waves; wave owns 64-gate-col slice. K phases: features(128) then h(256).
#define XS 392   // shorts/row: 384 + 8 pad  (784B; 784 % 128 == 16 -> conflict-free b128)
#define HS 264   // shorts/row: 256 + 8 pad  (528B; 528 % 128 == 16)
__global__ __launch_bounds__(256, 2) void gru_fused(
    const float* __restrict__ features, const float* __restrict__ h,
    const void* maskp, const int* __restrict__ mflagp,
    const __bf16* __restrict__ Wihb, const __bf16* __restrict__ Whhb, const __bf16* __restrict__ Wcb,
    const float* __restrict__ b_ih, const float* __restrict__ b_hh, const float* __restrict__ bcp,
    float* __restrict__ hout, __bf16* __restrict__ ctxb)
{
    __shared__ __bf16 Xs[32 * XS];
    __shared__ __bf16 Hn[32 * HS];
    int tid = threadIdx.x;
    int b0 = blockIdx.x * 32;
    int wv = tid >> 6, lane = tid & 63;
    int lan15 = lane & 15, kg = lane >> 4;    // kg in [0,4)
    int klo = kg * 8;
    int dsl = wv * 64;
    int mflag = mflagp[0];

    // stage features -> Xs[:, 0:128] (bf16)
#pragma unroll
    for (int it = 0; it < 4; ++it) {
        int idx = (it * 256 + tid) * 4;
        int r = idx >> 7, c = idx & 127;
        float4 vv = *(const float4*)&features[(size_t)(b0 + r) * F_ + c];
        ushort4 w = { bfbits(vv.x), bfbits(vv.y), bfbits(vv.z), bfbits(vv.w) };
        *reinterpret_cast<ushort4*>(&Xs[r * XS + c]) = w;
    }
    // stage h -> Xs[:, 128:384]
#pragma unroll
    for (int it = 0; it < 8; ++it) {
        int idx = (it * 256 + tid) * 4;
        int r = idx >> 8, c = idx & 255;
        float4 vv = *(const float4*)&h[(size_t)(b0 + r) * D_ + c];
        ushort4 w = { bfbits(vv.x), bfbits(vv.y), bfbits(vv.z), bfbits(vv.w) };
        *reinterpret_cast<ushort4*>(&Xs[r * XS + 128 + c]) = w;
    }
    // per-lane biases for this wave's d-slice
    float brv[4], bzv[4], biv[4], bhv[4], bcv[4];
#pragma unroll
    for (int nt = 0; nt < 4; ++nt) {
        int d = dsl + nt * 16 + lan15;
        brv[nt] = b_ih[d] + b_hh[d];
        bzv[nt] = b_ih[256 + d] + b_hh[256 + d];
        biv[nt] = b_ih[512 + d];
        bhv[nt] = b_hh[512 + d];
        bcv[nt] = bcp[d];
    }
    __syncthreads();

    f32x4 ar[2][4] = {}, az[2][4] = {}, ai[2][4] = {}, ah[2][4] = {};

    // Phase A: K over features, gates r,z,n_i
#pragma unroll
    for (int kb = 0; kb < 4; ++kb) {
        bf16x8 a0 = *reinterpret_cast<const bf16x8*>(&Xs[lan15 * XS + kb * 32 + klo]);
        bf16x8 a1 = *reinterpret_cast<const bf16x8*>(&Xs[(16 + lan15) * XS + kb * 32 + klo]);
#pragma unroll
        for (int nt = 0; nt < 4; ++nt) {
            int wr = dsl + nt * 16 + lan15;
            const __bf16* p = Wihb + (size_t)wr * F_ + kb * 32 + klo;
            bf16x8 br = *reinterpret_cast<const bf16x8*>(p);
            bf16x8 bz = *reinterpret_cast<const bf16x8*>(p + 256 * F_);
            bf16x8 bn = *reinterpret_cast<const bf16x8*>(p + 512 * F_);
            ar[0][nt] = __builtin_amdgcn_mfma_f32_16x16x32_bf16(a0, br, ar[0][nt], 0, 0, 0);
            ar[1][nt] = __builtin_amdgcn_mfma_f32_16x16x32_bf16(a1, br, ar[1][nt], 0, 0, 0);
            az[0][nt] = __builtin_amdgcn_mfma_f32_16x16x32_bf16(a0, bz, az[0][nt], 0, 0, 0);
            az[1][nt] = __builtin_amdgcn_mfma_f32_16x16x32_bf16(a1, bz, az[1][nt], 0, 0, 0);
            ai[0][nt] = __builtin_amdgcn_mfma_f32_16x16x32_bf16(a0, bn, ai[0][nt], 0, 0, 0);
            ai[1][nt] = __builtin_amdgcn_mfma_f32_16x16x32_bf16(a1, bn, ai[1][nt], 0, 0, 0);
        }
    }
    // Phase B: K over h, gates r,z,n_h
#pragma unroll
    for (int kb = 0; kb < 8; ++kb) {
        bf16x8 a0 = *reinterpret_cast<const bf16x8*>(&Xs[lan15 * XS + 128 + kb * 32 + klo]);
        bf16x8 a1 = *reinterpret_cast<const bf16x8*>(&Xs[(16 + lan15) * XS + 128 + kb * 32 + klo]);
#pragma unroll
        for (int nt = 0; nt < 4; ++nt) {
            int wr = dsl + nt * 16 + lan15;
            const __bf16* p = Whhb + (size_t)wr * D_ + kb * 32 + klo;
            bf16x8 br = *reinterpret_cast<const bf16x8*>(p);
            bf16x8 bz = *reinterpret_cast<const bf16x8*>(p + 256 * D_);
            bf16x8 bn = *reinterpret_cast<const bf16x8*>(p + 512 * D_);
            ar[0][nt] = __builtin_amdgcn_mfma_f32_16x16x32_bf16(a0, br, ar[0][nt], 0, 0, 0);
            ar[1][nt] = __builtin_amdgcn_mfma_f32_16x16x32_bf16(a1, br, ar[1][nt], 0, 0, 0);
            az[0][nt] = __builtin_amdgcn_mfma_f32_16x16x32_bf16(a0, bz, az[0][nt], 0, 0, 0);
            az[1][nt] = __builtin_amdgcn_mfma_f32_16x16x32_bf16(a1, bz, az[1][nt], 0, 0, 0);
            ah[0][nt] = __builtin_amdgcn_mfma_f32_16x16x32_bf16(a0, bn, ah[0][nt], 0, 0, 0);
            ah[1][nt] = __builtin_amdgcn_mfma_f32_16x16x32_bf16(a1, bn, ah[1][nt], 0, 0, 0);
        }
    }

    // gate epilogue: C layout col=lane&15, row=(lane>>4)*4+reg
#pragma unroll
    for (int mt = 0; mt < 2; ++mt) {
#pragma unroll
        for (int rg = 0; rg < 4; ++rg) {
            int row = mt * 16 + kg * 4 + rg;
            int grow = b0 + row;
            bool m = get_mask(maskp, mflag, grow);
#pragma unroll
            for (int nt = 0; nt < 4; ++nt) {
                int d = dsl + nt * 16 + lan15;
                float hv = (float)Xs[row * XS + 128 + d];
                float rv = sigmoid_fast(ar[mt][nt][rg] + brv[nt]);
                float zv = sigmoid_fast(az[mt][nt][rg] + bzv[nt]);
                float nv = tanh_fast(ai[mt][nt][rg] + biv[nt] + rv * (ah[mt][nt][rg] + bhv[nt]));
                float hn = (1.0f - zv) * nv + zv * hv;
                Hn[row * HS + d] = (__bf16)hn;
                hout[(size_t)grow * D_ + d] = m ? hn : hv;
            }
        }
    }
    __syncthreads();

    // ctx = h_new @ Wc.T + bc  (K=256), output bf16
    f32x4 ac[2][4] = {};
#pragma unroll
    for (int kb = 0; kb < 8; ++kb) {
        bf16x8 a0 = *reinterpret_cast<const bf16x8*>(&Hn[lan15 * HS + kb * 32 + klo]);
        bf16x8 a1 = *reinterpret_cast<const bf16x8*>(&Hn[(16 + lan15) * HS + kb * 32 + klo]);
#pragma unroll
        for (int nt = 0; nt < 4; ++nt) {
            int wr = dsl + nt * 16 + lan15;
            bf16x8 b = *reinterpret_cast<const bf16x8*>(&Wcb[(size_t)wr * D_ + kb * 32 + klo]);
            ac[0][nt] = __builtin_amdgcn_mfma_f32_16x16x32_bf16(a0, b, ac[0][nt], 0, 0, 0);
            ac[1][nt] = __builtin_amdgcn_mfma_f32_16x16x32_bf16(a1, b, ac[1][nt], 0, 0, 0);
        }
    }
#pragma unroll
    for (int mt = 0; mt < 2; ++mt) {
#pragma unroll
        for (int rg = 0; rg < 4; ++rg) {
            int row = mt * 16 + kg * 4 + rg;
#pragma unroll
            for (int nt = 0; nt < 4; ++nt) {
                int d = dsl + nt * 16 + lan15;
                ctxb[(size_t)(b0 + row) * D_ + d] = (__bf16)(ac[mt][nt][rg] + bcv[nt]);
            }
        }
    }
}

// ---- attention: lane=(t-slot, a-group16), 4 rows/wave, 16 rows/block ----
__global__ __launch_bounds__(256) void attn2(
    const __bf16* __restrict__ ctxb, const __bf16* __restrict__ tokpb,
    const __bf16* __restrict__ histb, const float* __restrict__ v,
    const float* __restrict__ accum, const void* maskp, const int* __restrict__ mflagp,
    float* __restrict__ out_emb)
{
    __shared__ __bf16 tls[T_ * A_];   // 32KB: tokp, then hist
    __shared__ float sls[16 * T_];    // 4KB scores/weights
    int tid = threadIdx.x;
    int b0 = blockIdx.x * 16;
    int wv = tid >> 6, lane = tid & 63;
    int ts = lane >> 4, ag = lane & 15;
    int mflag = mflagp[0];

    for (int j = tid; j < T_ * A_ / 4; j += 256)
        ((ushort4*)tls)[j] = ((const ushort4*)tokpb)[j];

    int a0 = ag * 16;
    float v2[16];
#pragma unroll
    for (int j = 0; j < 16; ++j) v2[j] = 2.0f * v[a0 + j];

    // ctx slice (x2 folded in): cc[r][j] = 2*ctx[row][a0+j]
    float cc[4][16];
#pragma unroll
    for (int r = 0; r < 4; ++r) {
        size_t row = (size_t)(b0 + wv * 4 + r);
        bf16x8 c0 = *(const bf16x8*)&ctxb[row * A_ + a0];
        bf16x8 c1 = *(const bf16x8*)&ctxb[row * A_ + a0 + 8];
#pragma unroll
        for (int j = 0; j < 8; ++j) { cc[r][j] = 2.0f * (float)c0[j]; cc[r][8 + j] = 2.0f * (float)c1[j]; }
    }
    __syncthreads();

    // scores: score[t] = const - 2*sum_a v[a]/(1+exp(2*(tokp+ctx)))  (const dropped: softmax-invariant)
    for (int tc = 0; tc < 16; ++tc) {
        int t = tc * 4 + ts;
        bf16x8 k0 = *(const bf16x8*)&tls[t * A_ + a0];
        bf16x8 k1 = *(const bf16x8*)&tls[t * A_ + a0 + 8];
        float tk[16];
#pragma unroll
        for (int j = 0; j < 8; ++j) { tk[j] = 2.0f * (float)k0[j]; tk[8 + j] = 2.0f * (float)k1[j]; }
        float p[4] = {0.f, 0.f, 0.f, 0.f};
#pragma unroll
        for (int j = 0; j < 16; ++j) {
#pragma unroll
            for (int r = 0; r < 4; ++r) {
                float e = __expf(tk[j] + cc[r][j]);
                p[r] = fmaf(-v2[j], __builtin_amdgcn_rcpf(e + 1.0f), p[r]);
            }
        }
#pragma unroll
        for (int r = 0; r < 4; ++r) {
#pragma unroll
            for (int m = 1; m < 16; m <<= 1) p[r] += __shfl_xor(p[r], m, 64);
            if (ag == 0) sls[(wv * 4 + r) * T_ + t] = p[r];
        }
    }
    __syncthreads();   // all waves done reading tokp from tls

    // softmax over T (lane = t); rows owned by this wave -> intra-wave LDS deps only
    float wgt[4];
#pragma unroll
    for (int r = 0; r < 4; ++r) {
        float x = sls[(wv * 4 + r) * T_ + lane];
        float mx = x;
#pragma unroll
        for (int m = 1; m < 64; m <<= 1) mx = fmaxf(mx, __shfl_xor(mx, m, 64));
        float e = __expf(x - mx);
        float s = e;
#pragma unroll
        for (int m = 1; m < 64; m <<= 1) s += __shfl_xor(s, m, 64);
        wgt[r] = e * __builtin_amdgcn_rcpf(s);
    }
#pragma unroll
    for (int r = 0; r < 4; ++r) sls[(wv * 4 + r) * T_ + lane] = wgt[r];

    // restage hist over tokp
    for (int j = tid; j < T_ * D_ / 4; j += 256)
        ((ushort4*)tls)[j] = ((const ushort4*)histb)[j];
    __syncthreads();

    // emb = weights @ hist ; lane owns d-quad
    int d0 = lane * 4;
    float acc4[4][4] = {};
    for (int t = 0; t < T_; ++t) {
        ushort4 hb = *reinterpret_cast<const ushort4*>(&tls[t * D_ + d0]);
        float hf0 = bits2f(hb.x), hf1 = bits2f(hb.y), hf2 = bits2f(hb.z), hf3 = bits2f(hb.w);
#pragma unroll
        for (int r = 0; r < 4; ++r) {
            float wt = sls[(wv * 4 + r) * T_ + t];
            acc4[r][0] = fmaf(wt, hf0, acc4[r][0]);
            acc4[r][1] = fmaf(wt, hf1, acc4[r][1]);
            acc4[r][2] = fmaf(wt, hf2, acc4[r][2]);
            acc4[r][3] = fmaf(wt, hf3, acc4[r][3]);
        }
    }
#pragma unroll
    for (int r = 0; r < 4; ++r) {
        size_t row = (size_t)(b0 + wv * 4 + r);
        bool m = get_mask(maskp, mflag, (int)row);
        float4 av = *(const float4*)&accum[row * D_ + d0];
        float4 o;
        o.x = m ? fmaf(av.x, DECAY_, acc4[r][0]) : av.x;
        o.y = m ? fmaf(av.y, DECAY_, acc4[r][1]) : av.y;
        o.z = m ? fmaf(av.z, DECAY_, acc4[r][2]) : av.z;
        o.w = m ? fmaf(av.w, DECAY_, acc4[r][3]) : av.w;
        *(float4*)&out_emb[row * D_ + d0] = o;
    }
}

extern "C" void kernel_launch(void* const* d_in, const int* in_sizes, int n_in,
                              void* d_out, int out_size, void* d_ws, size_t ws_size,
                              hipStream_t stream) {
    const float* features = (const float*)d_in[0];
    const float* h        = (const float*)d_in[1];
    const float* accum    = (const float*)d_in[2];
    const void*  maskp    = d_in[3];
    const float* tokens   = (const float*)d_in[4];
    const float* Wih      = (const float*)d_in[5];
    const float* Whh      = (const float*)d_in[6];
    const float* bih      = (const float*)d_in[7];
    const float* bhh      = (const float*)d_in[8];
    const float* Wh       = (const float*)d_in[9];
    const float* bh       = (const float*)d_in[10];
    const float* Wc       = (const float*)d_in[11];
    const float* bc       = (const float*)d_in[12];
    const float* v        = (const float*)d_in[13];
    // d_in[14] = bv : softmax-invariant, unused

    float* out = (float*)d_out;  // [B*D] emb_out, then [B*D] h_out

    __bf16* Wihb  = (__bf16*)d_ws;                 // 768*128
    __bf16* Whhb  = Wihb + 768 * 128;              // 768*256
    __bf16* Wcb   = Whhb + 768 * 256;              // 256*256
    __bf16* histb = Wcb + 256 * 256;               // 64*256
    __bf16* tokpb = histb + 64 * 256;              // 64*256
    __bf16* ctxb  = tokpb + 64 * 256;              // B*256
    int*    mflag = (int*)(ctxb + (size_t)B_ * D_);

    hipLaunchKernelGGL(mask_probe, dim3(1), dim3(256), 0, stream,
                       (const unsigned int*)maskp, mflag);
    hipLaunchKernelGGL(convert_w, dim3(352), dim3(256), 0, stream,
                       Wih, Whh, Wc, Wihb, Whhb, Wcb);
    hipLaunchKernelGGL(prep_kernel, dim3(64), dim3(256), 0, stream,
                       tokens, Wh, bh, histb, tokpb);
    hipLaunchKernelGGL(gru_fused, dim3(B_ / 32), dim3(256), 0, stream,
                       features, h, maskp, mflag, Wihb, Whhb, Wcb, bih, bhh, bc,
                       out + (size_t)B_ * D_, ctxb);
    hipLaunchKernelGGL(attn2, dim3(B_ / 16), dim3(256), 0, stream,
                       ctxb, tokpb, histb, v, accum, maskp, mflag, out);
}